// Round 1
// baseline (212.522 us; speedup 1.0000x reference)
//
#include <hip/hip_runtime.h>
#include <hip/hip_bf16.h>

using u32 = unsigned int;
using u16 = unsigned short;

// Problem constants (match reference; E taken from in_sizes at runtime)
#define NGR   512     // graphs
#define NF    128     // edge features
#define GF    64      // global features
#define HID   64      // hidden
#define IN1   192     // GF + NF

// counting-sort tiling
#define HT    256                 // threads for hist/scatter
#define ITEMS 10                  // edges per thread
#define EPB   (HT * ITEMS)        // 2560 edges per block (divides 1.6M exactly)

__global__ void zero_counts_kernel(u32* __restrict__ counts) {
    counts[threadIdx.x] = 0u;     // <<<1,512>>>
}

__global__ void hist_kernel(const int* __restrict__ ei0,
                            const int* __restrict__ batch,
                            u32* __restrict__ g_counts, int E) {
    __shared__ u32 h[NGR];
    int tid = threadIdx.x;
    h[tid] = 0u; h[tid + 256] = 0u;
    __syncthreads();
    int base = blockIdx.x * EPB + tid;
#pragma unroll
    for (int i = 0; i < ITEMS; ++i) {
        int e = base + i * HT;
        if (e < E) {
            int s = batch[ei0[e]];
            atomicAdd(&h[s], 1u);
        }
    }
    __syncthreads();
    u32 v0 = h[tid];       if (v0) atomicAdd(&g_counts[tid], v0);
    u32 v1 = h[tid + 256]; if (v1) atomicAdd(&g_counts[tid + 256], v1);
}

__global__ void scan_kernel(const u32* __restrict__ counts,
                            u32* __restrict__ offsets,
                            u32* __restrict__ cursor) {
    // <<<1,512>>> exclusive scan over 512 bins (Hillis-Steele, ping-pong)
    __shared__ u32 A[NGR], B[NGR];
    int t = threadIdx.x;
    u32 c = counts[t];
    A[t] = c;
    __syncthreads();
    u32* src = A; u32* dst = B;
    for (int off = 1; off < NGR; off <<= 1) {
        u32 v = src[t];
        if (t >= off) v += src[t - off];
        dst[t] = v;
        __syncthreads();
        u32* tmp = src; src = dst; dst = tmp;
    }
    u32 exc = src[t] - c;
    offsets[t] = exc;
    cursor[t]  = exc;
}

__global__ void scatter_kernel(const int* __restrict__ ei0,
                               const int* __restrict__ batch,
                               u32* __restrict__ cursor,
                               u32* __restrict__ sorted, int E) {
    __shared__ u32 h[NGR];
    __shared__ u32 bs[NGR];
    int tid = threadIdx.x;
    h[tid] = 0u; h[tid + 256] = 0u;
    __syncthreads();
    int base = blockIdx.x * EPB + tid;
    u16 segs[ITEMS];
    u16 ranks[ITEMS];
#pragma unroll
    for (int i = 0; i < ITEMS; ++i) {
        int e = base + i * HT;
        if (e < E) {
            int s = batch[ei0[e]];
            segs[i]  = (u16)s;
            ranks[i] = (u16)atomicAdd(&h[s], 1u);  // rank < EPB fits u16
        }
    }
    __syncthreads();
    u32 v0 = h[tid];       if (v0) bs[tid]       = atomicAdd(&cursor[tid], v0);
    u32 v1 = h[tid + 256]; if (v1) bs[tid + 256] = atomicAdd(&cursor[tid + 256], v1);
    __syncthreads();
#pragma unroll
    for (int i = 0; i < ITEMS; ++i) {
        int e = base + i * HT;
        if (e < E) {
            sorted[bs[segs[i]] + ranks[i]] = (u32)e;
        }
    }
}

__launch_bounds__(512, 1)
__global__ void reduce_mlp_kernel(const float* __restrict__ edge_attr,
                                  const u32* __restrict__ sorted,
                                  const u32* __restrict__ counts,
                                  const u32* __restrict__ offsets,
                                  const float* __restrict__ u,
                                  const float* __restrict__ W1,
                                  const float* __restrict__ b1,
                                  const float* __restrict__ W2,
                                  const float* __restrict__ b2,
                                  float* __restrict__ out) {
    __shared__ float sW1[IN1 * HID];   // 48 KB
    __shared__ float sW2[HID * GF];    // 16 KB
    __shared__ float sb1[HID];
    __shared__ float sb2[GF];
    __shared__ float red[16 * NF];     // 8 KB partial sums
    __shared__ float vin[IN1];         // [u_row | mean]
    __shared__ float hv[HID];

    int tid = threadIdx.x;
    int b   = blockIdx.x;

    // stage weights/biases/u-row into LDS (visible after first __syncthreads)
    for (int i = tid; i < IN1 * HID; i += 512) sW1[i] = W1[i];
    for (int i = tid; i < HID * GF;  i += 512) sW2[i] = W2[i];
    if (tid < HID) sb1[tid] = b1[tid];
    if (tid < GF)  { sb2[tid] = b2[tid]; vin[tid] = u[b * GF + tid]; }

    u32 off = offsets[b];
    u32 cnt = counts[b];
    int row  = tid >> 5;    // 0..15
    int lane = tid & 31;    // 0..31 -> float4 index within a 128-f row

    float4 a0 = make_float4(0.f, 0.f, 0.f, 0.f);
    float4 a1 = a0, a2 = a0, a3 = a0;

    u32 j = (u32)row;
    // 4-deep ILP: 4 independent row gathers in flight per thread
    for (; j + 48 < cnt; j += 64) {
        u32 e0 = sorted[off + j];
        u32 e1 = sorted[off + j + 16];
        u32 e2 = sorted[off + j + 32];
        u32 e3 = sorted[off + j + 48];
        float4 v0 = ((const float4*)(edge_attr + (size_t)e0 * NF))[lane];
        float4 v1 = ((const float4*)(edge_attr + (size_t)e1 * NF))[lane];
        float4 v2 = ((const float4*)(edge_attr + (size_t)e2 * NF))[lane];
        float4 v3 = ((const float4*)(edge_attr + (size_t)e3 * NF))[lane];
        a0.x += v0.x; a0.y += v0.y; a0.z += v0.z; a0.w += v0.w;
        a1.x += v1.x; a1.y += v1.y; a1.z += v1.z; a1.w += v1.w;
        a2.x += v2.x; a2.y += v2.y; a2.z += v2.z; a2.w += v2.w;
        a3.x += v3.x; a3.y += v3.y; a3.z += v3.z; a3.w += v3.w;
    }
    for (; j < cnt; j += 16) {
        u32 e = sorted[off + j];
        float4 v = ((const float4*)(edge_attr + (size_t)e * NF))[lane];
        a0.x += v.x; a0.y += v.y; a0.z += v.z; a0.w += v.w;
    }
    a0.x += a1.x + a2.x + a3.x;
    a0.y += a1.y + a2.y + a3.y;
    a0.z += a1.z + a2.z + a3.z;
    a0.w += a1.w + a2.w + a3.w;
    ((float4*)red)[row * 32 + lane] = a0;
    __syncthreads();

    if (tid < NF) {
        float s = 0.f;
#pragma unroll
        for (int r = 0; r < 16; ++r) s += red[r * NF + tid];
        vin[GF + tid] = s / fmaxf((float)cnt, 1.0f);   // scatter-mean (0 if empty)
    }
    __syncthreads();

    if (tid < HID) {
        float acc = sb1[tid];
#pragma unroll
        for (int k = 0; k < IN1; ++k) acc += vin[k] * sW1[k * HID + tid];
        hv[tid] = fmaxf(acc, 0.0f);
    }
    __syncthreads();

    if (tid < GF) {
        float acc = sb2[tid];
#pragma unroll
        for (int k = 0; k < HID; ++k) acc += hv[k] * sW2[k * GF + tid];
        out[b * GF + tid] = acc;
    }
}

extern "C" void kernel_launch(void* const* d_in, const int* in_sizes, int n_in,
                              void* d_out, int out_size, void* d_ws, size_t ws_size,
                              hipStream_t stream) {
    // inputs: 0:x(unused) 1:edge_index[2,E] 2:edge_attr[E,128] 3:u[512,64]
    //         4:batch[50000] 5:W1[192,64] 6:b1[64] 7:W2[64,64] 8:b2[64]
    const int*   ei        = (const int*)d_in[1];
    const float* edge_attr = (const float*)d_in[2];
    const float* u         = (const float*)d_in[3];
    const int*   batch     = (const int*)d_in[4];
    const float* W1        = (const float*)d_in[5];
    const float* b1        = (const float*)d_in[6];
    const float* W2        = (const float*)d_in[7];
    const float* b2        = (const float*)d_in[8];
    float*       out       = (float*)d_out;

    const int E = in_sizes[1] / 2;
    const int* ei0 = ei;   // row 0 of edge_index

    // workspace layout: sorted[E] | counts[512] | offsets[512] | cursor[512]
    u32* sorted  = (u32*)d_ws;
    u32* counts  = sorted + E;
    u32* offsets = counts + NGR;
    u32* cursor  = offsets + NGR;

    const int nblocks = (E + EPB - 1) / EPB;

    zero_counts_kernel<<<1, NGR, 0, stream>>>(counts);
    hist_kernel<<<nblocks, HT, 0, stream>>>(ei0, batch, counts, E);
    scan_kernel<<<1, NGR, 0, stream>>>(counts, offsets, cursor);
    scatter_kernel<<<nblocks, HT, 0, stream>>>(ei0, batch, cursor, sorted, E);
    reduce_mlp_kernel<<<NGR, 512, 0, stream>>>(edge_attr, sorted, counts, offsets,
                                               u, W1, b1, W2, b2, out);
}